// Round 15
// baseline (192.127 us; speedup 1.0000x reference)
//
#include <hip/hip_runtime.h>
#include <cstdint>
#include <cmath>

#define B_ 4
#define H_ 256
#define C_ 80
#define TX_ 256
#define TY_ 1024
#define NC_ 64                 // chunks of 16 columns
#define NEGF (-1e9f)

// output layout (floats): o_en_ex [B,H,TY] | logp [B,TX,TY] | attn [B,TX,TY] | dr [B,TX]
#define OFF_LOGP (B_*H_*TY_)
#define OFF_ATTN (OFF_LOGP + B_*TX_*TY_)
#define OFF_DR   (OFF_ATTN + B_*TX_*TY_)

// __shfl_up(x,1) as pure VALU: DPP wave_shr:1 (ctrl 0x138); lane 0 gets NEGF.
__device__ __forceinline__ float dpp_shr1_negfill_f32(float x) {
  union { float f; int i; } u, o, r;
  u.f = x; o.f = NEGF;
  r.i = __builtin_amdgcn_update_dpp(o.i, u.i, 0x138, 0xf, 0xf, false);
  return r.f;
}

// ---------------------------------------------------------------------------
// Kernel A: logp[b,x,t] = -0.5*mean_c((y-mu)^2*exp(-2 ls)) - 0.5*mean_c(ls)
// f64 math identical to the passing R5-R14 versions.  The transposed lpT
// store is GONE (k_dp now reads logp row-major directly) — removes a 4 MB
// partial-line (write-amplified) store + 16 KB LDS tile.
// ---------------------------------------------------------------------------
__global__ __launch_bounds__(256) void k_logp(
    const float* __restrict__ mu, const float* __restrict__ ls,
    const float* __restrict__ y, float* __restrict__ logp_out)
{
  const int b  = blockIdx.y;
  const int x0 = blockIdx.x * 4;
  const int tid = threadIdx.x;
  __shared__ double s_w[4][C_];
  __shared__ double s_m1[4][C_];
  __shared__ double s_wm2[4][C_];
  __shared__ double s_lsv[4][C_];
  __shared__ double s_K[4];
  __shared__ double s_t0[4];
  for (int i = tid; i < 4 * C_; i += 256) {
    int xi = i / C_, c = i - xi * C_;
    double m = (double)mu[(b * C_ + c) * TX_ + x0 + xi];
    double l = (double)ls[(b * C_ + c) * TX_ + x0 + xi];
    double w = exp(-2.0 * l);
    s_w[xi][c]   = w;
    s_m1[xi][c]  = -2.0 * w * m;
    s_wm2[xi][c] = w * m * m;
    s_lsv[xi][c] = l;
  }
  __syncthreads();
  {
    int xi = tid >> 6, cc = tid & 63;
    double kp = (cc < C_) ? s_wm2[xi][cc] : 0.0;
    double tp = (cc < C_) ? s_lsv[xi][cc] : 0.0;
    if (cc + 64 < C_) { kp += s_wm2[xi][cc + 64]; tp += s_lsv[xi][cc + 64]; }
#pragma unroll
    for (int off = 32; off; off >>= 1) {
      kp += __shfl_down(kp, off);
      tp += __shfl_down(tp, off);
    }
    if (cc == 0) { s_K[xi] = kp; s_t0[xi] = -0.5 * (tp * (1.0 / C_)); }
  }
  __syncthreads();

  const int t0 = tid * 4;
  double acc[4][4];
#pragma unroll
  for (int xi = 0; xi < 4; ++xi)
#pragma unroll
    for (int k = 0; k < 4; ++k) acc[xi][k] = 0.0;

  const float4* yp = (const float4*)(y + (size_t)b * C_ * TY_) + tid;
#pragma unroll 4
  for (int c = 0; c < C_; ++c) {
    float4 yv = yp[c * (TY_ / 4)];
    double y0 = yv.x, y1 = yv.y, y2 = yv.z, y3 = yv.w;
#pragma unroll
    for (int xi = 0; xi < 4; ++xi) {
      double w = s_w[xi][c], m1 = s_m1[xi][c];
      double u0 = fma(w, y0, m1), u1 = fma(w, y1, m1);
      double u2 = fma(w, y2, m1), u3 = fma(w, y3, m1);
      acc[xi][0] = fma(u0, y0, acc[xi][0]);
      acc[xi][1] = fma(u1, y1, acc[xi][1]);
      acc[xi][2] = fma(u2, y2, acc[xi][2]);
      acc[xi][3] = fma(u3, y3, acc[xi][3]);
    }
  }

#pragma unroll
  for (int xi = 0; xi < 4; ++xi) {
    int x = x0 + xi;
    double c0 = s_t0[xi], K = s_K[xi];
    float r[4];
#pragma unroll
    for (int k = 0; k < 4; ++k)
      r[k] = (float)((acc[xi][k] + K) * (-0.5 / C_) + c0);
    *(float4*)&logp_out[((size_t)(b * TX_ + x)) * TY_ + t0] =
        make_float4(r[0], r[1], r[2], r[3]);
  }
}

// ---------------------------------------------------------------------------
// Kernel B: Viterbi DP, 4 skewed waves per batch (thread = one x), reading
// logp ROW-MAJOR (each thread reads its own row: 4 float4 = one cacheline
// per phase; masking to NEGF done in registers OUTSIDE the chain).
// R14 root cause found: `const __restrict__` on the input licenses load
// rematerialization at use across ANY barrier/clobber — VGPR_Count=68
// proved buffers were never register-resident and every phase paid a full
// memory latency.  Fix: plain `const float*` (no restrict) + memory-clobber
// phase barrier => loads are pinned 3 phases ahead, values held in regs.
// Cross-wave handoff via LDS boundary series (skew 1 phase); lane63 batches
// its 16 boundary values in regs -> 4 ds_write_b128 after the chain.
// Phase barrier drains LDS only (lgkmcnt) — global prefetches stay in
// flight.  DP math bit-identical to R12-R14 (same values, same op order).
// LDS: bits 32KB + dur 1KB + bdry 640B.
// ---------------------------------------------------------------------------
#define PHASE_BAR() \
  asm volatile("s_waitcnt lgkmcnt(0)\n\ts_barrier" ::: "memory")

#define PHASEQ(FL, FC, q)                                                   \
  {                                                                         \
    const int cl = (q) - w;                                                 \
    const int clc = cl < 0 ? 0 : (cl >= NC_ ? NC_ - 1 : cl);                \
    const float4* cb = (const float4*)(myrow + clc * 16);                   \
    FL[0] = cb[0]; FL[1] = cb[1]; FL[2] = cb[2]; FL[3] = cb[3];             \
    const int cc = (q) - 3 - w;                                             \
    if (cc >= 0 && cc < NC_) {                                              \
      if (cc == 0) { v = (tid == 0) ? 0.0f : NEGF; word = 0u; }             \
      const uint32_t bitbase = 1u << ((cc & 1) << 4);                       \
      const float* bp = &bdry[cc & 1][w][0];                                \
      float bv[16];                                                         \
      *(float4*)&bv[0]  = *(const float4*)(bp);                             \
      *(float4*)&bv[4]  = *(const float4*)(bp + 4);                         \
      *(float4*)&bv[8]  = *(const float4*)(bp + 8);                         \
      *(float4*)&bv[12] = *(const float4*)(bp + 12);                        \
      const int tb = cc * 16;                                               \
      float fv[16];                                                         \
      _Pragma("unroll")                                                     \
      for (int i = 0; i < 16; ++i) {                                        \
        float raw = ((const float*)FC)[i];                                  \
        fv[i] = (xm && (tb + i) < ylen) ? raw : NEGF;                       \
      }                                                                     \
      float bs[16];                                                         \
      bs[0] = v;                                                            \
      _Pragma("unroll")                                                     \
      for (int i = 0; i < 16; ++i) {                                        \
        float vl = dpp_shr1_negfill_f32(v);                                 \
        if (amlane0) vl = bv[i];                                            \
        if (vl > v) word |= (bitbase << i);                                 \
        float nv = fv[i] + fmaxf(v, vl);                                    \
        if (i < 15) bs[i + 1] = nv;                                         \
        v = nv;                                                             \
      }                                                                     \
      if (lane == 63) {                                                     \
        float* wr = &bdry[cc & 1][w + 1][0];                                \
        *(float4*)(wr)      = *(float4*)&bs[0];                             \
        *(float4*)(wr + 4)  = *(float4*)&bs[4];                             \
        *(float4*)(wr + 8)  = *(float4*)&bs[8];                             \
        *(float4*)(wr + 12) = *(float4*)&bs[12];                            \
      }                                                                     \
      if (cc & 1) { bits[(cc >> 1) * 256 + tid] = word; word = 0u; }        \
    }                                                                       \
    PHASE_BAR();                                                            \
  }

__global__ __launch_bounds__(256, 1) void k_dp(
    const float* lpg,                       // NO __restrict__ — see header
    const int* __restrict__ xlp, const int* __restrict__ ylp,
    float* __restrict__ dr_out, int* __restrict__ cum_ws,
    int* __restrict__ xt_ws)
{
  const int b = blockIdx.x;
  const int tid = threadIdx.x;            // = x
  const int lane = tid & 63;
  const int w = tid >> 6;                 // wave id 0..3
  __shared__ uint32_t bits[8192];         // [wword*256 + x], 32 KB
  __shared__ uint32_t dur[TX_];
  __shared__ float bdry[2][5][16];        // [chunk parity][dest wave][col]

  const float* myrow = lpg + ((size_t)(b * TX_ + tid)) * TY_;
  const int xlen = xlp[b], ylen = ylp[b];
  const bool xm = tid < xlen;
  const bool amlane0 = (w > 0) && (lane == 0);

  float v = NEGF;                         // set properly at cc==0
  uint32_t word = 0;
  float4 f0[4], f1[4], f2[4], f3[4];

  // phases q=0..71: wave w loads chunk clamp(q-w), consumes chunk q-3-w.
  for (int q = 0; q < 72; q += 4) {
    PHASEQ(f0, f1, q);
    PHASEQ(f1, f2, q + 1);
    PHASEQ(f2, f3, q + 2);
    PHASEQ(f3, f0, q + 3);
  }
  __syncthreads();

  dur[tid] = 0;
  __syncthreads();

  if (tid == 0) {
    int idx = xlen - 1;
    int t = ylen - 1;
    while (t >= 0) {
      if (idx == 0) { dur[0] = (uint32_t)(t + 1); break; }
      int ww = t >> 5, rr = t & 31;
      uint32_t wd = bits[ww * 256 + idx];
      wd &= (rr == 31) ? 0xffffffffu : ((1u << (rr + 1)) - 1u);
      while (wd == 0 && ww > 0) { --ww; wd = bits[ww * 256 + idx]; }
      if (wd == 0) { dur[idx] = (uint32_t)(t + 1); break; }
      int bitpos = 31 - __builtin_clz(wd);
      int tp = (ww << 5) | bitpos;       // step where diag fires -> decrement
      dur[idx] = (uint32_t)(t - tp + 1); // first visit of idx -> plain store
      --idx;
      t = tp - 1;
    }
  }
  __syncthreads();

  if (w == 0) {
    // wave-wide inclusive scan of durations -> cum, dr, and t->x scatter map
    uint32_t d0 = dur[4 * lane], d1 = dur[4 * lane + 1];
    uint32_t d2 = dur[4 * lane + 2], d3 = dur[4 * lane + 3];
    uint32_t own = d0 + d1 + d2 + d3;
    uint32_t s = own;
#pragma unroll
    for (int off = 1; off < 64; off <<= 1) {
      uint32_t n = __shfl_up(s, off);
      if (lane >= off) s += n;
    }
    uint32_t base = s - own;
    uint32_t c0 = base + d0, c1 = c0 + d1, c2 = c1 + d2, c3 = c2 + d3;
    int x = 4 * lane;
    cum_ws[b * TX_ + x]     = (int)c0;
    cum_ws[b * TX_ + x + 1] = (int)c1;
    cum_ws[b * TX_ + x + 2] = (int)c2;
    cum_ws[b * TX_ + x + 3] = (int)c3;
    dr_out[b * TX_ + x]     = (float)d0;
    dr_out[b * TX_ + x + 1] = (float)d1;
    dr_out[b * TX_ + x + 2] = (float)d2;
    dr_out[b * TX_ + x + 3] = (float)d3;
    int* xt = xt_ws + b * TY_;
    for (uint32_t t = c0 - d0; t < c0; ++t) xt[t] = x;
    for (uint32_t t = c1 - d1; t < c1; ++t) xt[t] = x + 1;
    for (uint32_t t = c2 - d2; t < c2; ++t) xt[t] = x + 2;
    for (uint32_t t = c3 - d3; t < c3; ++t) xt[t] = x + 3;
  }
}

// ---------------------------------------------------------------------------
// Kernel C (fused epilogue): blocks [0,TX) write attn rows from cum;
// blocks [TX,TX+H) gather o_en_ex[b,h,t] = t<ylen ? en[b,h,xt[b,t]] : 0.
// ---------------------------------------------------------------------------
__global__ __launch_bounds__(256) void k_epi(
    const int* __restrict__ cum_ws, const int* __restrict__ xt_ws,
    const float* __restrict__ en, const int* __restrict__ ylp,
    float* __restrict__ attn, float* __restrict__ oen)
{
  const int b = blockIdx.y, bx = blockIdx.x, tid = threadIdx.x;
  __shared__ float row[TX_];
  if (bx < TX_) {
    const int x = bx;
    int hi = cum_ws[b * TX_ + x];
    int lo = (x > 0) ? cum_ws[b * TX_ + x - 1] : 0;
    int t0 = tid * 4;
    float4 v;
    v.x = (t0     >= lo && t0     < hi) ? 1.f : 0.f;
    v.y = (t0 + 1 >= lo && t0 + 1 < hi) ? 1.f : 0.f;
    v.z = (t0 + 2 >= lo && t0 + 2 < hi) ? 1.f : 0.f;
    v.w = (t0 + 3 >= lo && t0 + 3 < hi) ? 1.f : 0.f;
    *(float4*)&attn[((size_t)(b * TX_ + x)) * TY_ + t0] = v;
  } else {
    const int h = bx - TX_;
    row[tid] = en[((size_t)(b * H_ + h)) * TX_ + tid];
    __syncthreads();
    const int ylen = ylp[b];
    int t0 = tid * 4;
    int4 xi = *(const int4*)&xt_ws[b * TY_ + t0];
    float4 v;
    v.x = (t0     < ylen) ? row[xi.x & (TX_ - 1)] : 0.f;
    v.y = (t0 + 1 < ylen) ? row[xi.y & (TX_ - 1)] : 0.f;
    v.z = (t0 + 2 < ylen) ? row[xi.z & (TX_ - 1)] : 0.f;
    v.w = (t0 + 3 < ylen) ? row[xi.w & (TX_ - 1)] : 0.f;
    *(float4*)&oen[((size_t)(b * H_ + h)) * TY_ + t0] = v;
  }
}

extern "C" void kernel_launch(void* const* d_in, const int* in_sizes, int n_in,
                              void* d_out, int out_size, void* d_ws, size_t ws_size,
                              hipStream_t stream)
{
  const float* en = (const float*)d_in[0];
  const float* mu = (const float*)d_in[1];
  const float* ls = (const float*)d_in[2];
  const float* y  = (const float*)d_in[3];
  const int*   xl = (const int*)d_in[4];
  const int*   yl = (const int*)d_in[5];

  float* out  = (float*)d_out;
  float* oen  = out;             // [B,H,TY]
  float* logp = out + OFF_LOGP;  // [B,TX,TY]
  float* attn = out + OFF_ATTN;  // [B,TX,TY]
  float* dr   = out + OFF_DR;    // [B,TX]

  int* cum = (int*)d_ws;               // B*TX ints
  int* xt  = cum + B_ * TX_;           // B*TY ints

  k_logp<<<dim3(TX_ / 4, B_),   256, 0, stream>>>(mu, ls, y, logp);
  k_dp  <<<B_,                  256, 0, stream>>>(logp, xl, yl, dr, cum, xt);
  k_epi <<<dim3(TX_ + H_, B_),  256, 0, stream>>>(cum, xt, en, yl, attn, oen);
}